// Round 3
// baseline (82.522 us; speedup 1.0000x reference)
//
#include <hip/hip_runtime.h>

#define D 256
#define NBLOCKS 2048
#define WAVES_PER_BLOCK 4
#define EPS 1e-8f

__global__ __launch_bounds__(256) void gc_partial(
    const float* __restrict__ feat,
    const int* __restrict__ known,
    const int* __restrict__ unknown,
    float* __restrict__ acc,   // [3*D]: s_all | s_known | s_unknown
    int N)
{
    const int lane = threadIdx.x & 63;
    const int wave = threadIdx.x >> 6;
    const int gw   = blockIdx.x * WAVES_PER_BLOCK + wave;
    const int nw   = gridDim.x * WAVES_PER_BLOCK;

    float4 aAll = {0.f, 0.f, 0.f, 0.f};
    float4 aK   = {0.f, 0.f, 0.f, 0.f};
    float4 aU   = {0.f, 0.f, 0.f, 0.f};

    // 4 consecutive rows per wave-iteration: 4 independent 1KB loads +
    // one int4 load per mask -> 4KB+32B in flight, 4 interleaved reduce chains.
    for (int r = gw * 4; r < N; r += nw * 4) {
        if (r + 4 <= N) {
            const float4* rp = (const float4*)(feat + (size_t)r * D);
            float4 v0 = rp[lane];
            float4 v1 = rp[64 + lane];
            float4 v2 = rp[128 + lane];
            float4 v3 = rp[192 + lane];
            int4 km = *(const int4*)(known + r);    // r % 4 == 0 -> 16B aligned
            int4 um = *(const int4*)(unknown + r);

            float s0 = v0.x*v0.x + v0.y*v0.y + v0.z*v0.z + v0.w*v0.w;
            float s1 = v1.x*v1.x + v1.y*v1.y + v1.z*v1.z + v1.w*v1.w;
            float s2 = v2.x*v2.x + v2.y*v2.y + v2.z*v2.z + v2.w*v2.w;
            float s3 = v3.x*v3.x + v3.y*v3.y + v3.z*v3.z + v3.w*v3.w;
            #pragma unroll
            for (int off = 32; off > 0; off >>= 1) {   // 4 independent chains
                s0 += __shfl_xor(s0, off);
                s1 += __shfl_xor(s1, off);
                s2 += __shfl_xor(s2, off);
                s3 += __shfl_xor(s3, off);
            }
            float i0 = 1.0f / fmaxf(sqrtf(s0), EPS);
            float i1 = 1.0f / fmaxf(sqrtf(s1), EPS);
            float i2 = 1.0f / fmaxf(sqrtf(s2), EPS);
            float i3 = 1.0f / fmaxf(sqrtf(s3), EPS);

            float4 u0 = {v0.x*i0, v0.y*i0, v0.z*i0, v0.w*i0};
            float4 u1 = {v1.x*i1, v1.y*i1, v1.z*i1, v1.w*i1};
            float4 u2 = {v2.x*i2, v2.y*i2, v2.z*i2, v2.w*i2};
            float4 u3 = {v3.x*i3, v3.y*i3, v3.z*i3, v3.w*i3};

            float k0 = km.x ? 1.f : 0.f, k1 = km.y ? 1.f : 0.f;
            float k2 = km.z ? 1.f : 0.f, k3 = km.w ? 1.f : 0.f;
            float w0 = um.x ? 1.f : 0.f, w1 = um.y ? 1.f : 0.f;
            float w2 = um.z ? 1.f : 0.f, w3 = um.w ? 1.f : 0.f;

            aAll.x += u0.x + u1.x + u2.x + u3.x;
            aAll.y += u0.y + u1.y + u2.y + u3.y;
            aAll.z += u0.z + u1.z + u2.z + u3.z;
            aAll.w += u0.w + u1.w + u2.w + u3.w;

            aK.x += u0.x*k0 + u1.x*k1 + u2.x*k2 + u3.x*k3;
            aK.y += u0.y*k0 + u1.y*k1 + u2.y*k2 + u3.y*k3;
            aK.z += u0.z*k0 + u1.z*k1 + u2.z*k2 + u3.z*k3;
            aK.w += u0.w*k0 + u1.w*k1 + u2.w*k2 + u3.w*k3;

            aU.x += u0.x*w0 + u1.x*w1 + u2.x*w2 + u3.x*w3;
            aU.y += u0.y*w0 + u1.y*w1 + u2.y*w2 + u3.y*w3;
            aU.z += u0.z*w0 + u1.z*w1 + u2.z*w2 + u3.z*w3;
            aU.w += u0.w*w0 + u1.w*w1 + u2.w*w2 + u3.w*w3;
        } else {
            for (int q = r; q < N; ++q) {
                const float4* rp = (const float4*)(feat + (size_t)q * D);
                float4 v = rp[lane];
                float ss = v.x*v.x + v.y*v.y + v.z*v.z + v.w*v.w;
                #pragma unroll
                for (int off = 32; off > 0; off >>= 1) ss += __shfl_xor(ss, off);
                float inv = 1.0f / fmaxf(sqrtf(ss), EPS);
                float4 u = {v.x*inv, v.y*inv, v.z*inv, v.w*inv};
                float kk = known[q] ? 1.f : 0.f;
                float ww = unknown[q] ? 1.f : 0.f;
                aAll.x += u.x; aAll.y += u.y; aAll.z += u.z; aAll.w += u.w;
                aK.x += u.x*kk; aK.y += u.y*kk; aK.z += u.z*kk; aK.w += u.w*kk;
                aU.x += u.x*ww; aU.y += u.y*ww; aU.z += u.z*ww; aU.w += u.w*ww;
            }
        }
    }

    // block reduce: wave w writes its 256-col partial; 256 threads sum columns
    __shared__ float red[WAVES_PER_BLOCK][D];
    float4 accs[3] = {aAll, aK, aU};
    #pragma unroll
    for (int a = 0; a < 3; ++a) {
        float4 t = accs[a];
        red[wave][lane * 4 + 0] = t.x;
        red[wave][lane * 4 + 1] = t.y;
        red[wave][lane * 4 + 2] = t.z;
        red[wave][lane * 4 + 3] = t.w;
        __syncthreads();
        const int col = threadIdx.x;
        float s = red[0][col] + red[1][col] + red[2][col] + red[3][col];
        atomicAdd(acc + a * D + col, s);
        __syncthreads();
    }
}

__global__ __launch_bounds__(256) void gc_final(
    const float* __restrict__ acc, float* __restrict__ out, int N)
{
    const int d = threadIdx.x;
    const float sa = acc[d];
    const float sk = acc[D + d];
    const float su = acc[2 * D + d];
    float p1 = sa * sk;
    float p2 = sk * sk;
    float p3 = sk * su;
    #pragma unroll
    for (int off = 32; off > 0; off >>= 1) {
        p1 += __shfl_xor(p1, off);
        p2 += __shfl_xor(p2, off);
        p3 += __shfl_xor(p3, off);
    }
    __shared__ float r[3][WAVES_PER_BLOCK];
    const int wave = threadIdx.x >> 6, lane = threadIdx.x & 63;
    if (lane == 0) { r[0][wave] = p1; r[1][wave] = p2; r[2][wave] = p3; }
    __syncthreads();
    if (threadIdx.x == 0) {
        float t1 = r[0][0] + r[0][1] + r[0][2] + r[0][3];
        float t2 = r[1][0] + r[1][1] + r[1][2] + r[1][3];
        float t3 = r[2][0] + r[2][1] + r[2][2] + r[2][3];
        float gain = t1 - 0.5f * t2 - t3;   // LAMDA=0.5, ETA=1.0
        out[0] = -gain / (float)N;
    }
}

extern "C" void kernel_launch(void* const* d_in, const int* in_sizes, int n_in,
                              void* d_out, int out_size, void* d_ws, size_t ws_size,
                              hipStream_t stream) {
    const float* feat = (const float*)d_in[0];
    const int* known = (const int*)d_in[1];
    const int* unknown = (const int*)d_in[2];
    const int N = in_sizes[1];
    float* acc = (float*)d_ws;   // 3*D floats

    hipMemsetAsync(acc, 0, 3 * D * sizeof(float), stream);
    gc_partial<<<NBLOCKS, 256, 0, stream>>>(feat, known, unknown, acc, N);
    gc_final<<<1, 256, 0, stream>>>(acc, (float*)d_out, N);
}